// Round 13
// baseline (96.021 us; speedup 1.0000x reference)
//
#include <hip/hip_runtime.h>
#include <hip/hip_bf16.h>

#define B 16
#define N 10000
#define D 64
#define R 64
#define H 512
#define K 32
#define NRBF 79                      // ceil(10000 / 128) rbf blocks per b
#define NBUCK 4096

typedef unsigned long long ull;
typedef short s16x8 __attribute__((ext_vector_type(8)));
typedef float f32x16 __attribute__((ext_vector_type(16)));

// ---------- ws layout (bytes) ----------
// ow   : B*K f32      @ 0        (2048)
// nm2  : B*K f32      @ 2048     (2048)   -0.5*||mean||^2
// tmh  : B*K*D bf16   @ 4096     (65536)  mean hi
// tml  : B*K*D bf16   @ 69632    (65536)  mean lo
// part : B*NRBF f32   @ 135168   (5056)

static __device__ __forceinline__ ushort f2bf_bits(float x) {
    __hip_bfloat16 h = __float2bfloat16(x);
    return *reinterpret_cast<ushort*>(&h);
}
// split 8 floats (two float4) into bf16 hi / lo fragments
static __device__ __forceinline__ void split8(const float4 a, const float4 b,
                                              s16x8& hi, s16x8& lo) {
    const float v[8] = {a.x, a.y, a.z, a.w, b.x, b.y, b.z, b.w};
    #pragma unroll
    for (int i = 0; i < 8; ++i) {
        const ushort h = f2bf_bits(v[i]);
        const float hf = __uint_as_float(((unsigned)h) << 16);
        hi[i] = (short)h;
        lo[i] = (short)f2bf_bits(v[i] - hf);
    }
}

// ---------------- kernel 1: fused top-K + MLP (one block per b) -------------
// Phase A: exact top-K SET via histogram select (order irrelevant downstream:
// sum over k; rank gives value-determined slots; key = val_bits<<32 | ~idx
// keeps jax's smaller-index tie-break). oidx stays in LDS.
// Phase B: MLP on the 32 selected rows: h = relu(rp + W1[:,R:] @ s);
// mean = W2 @ h + b2 -> bf16 hi/lo + nm2. All b-local, no extra dispatch.
__global__ __launch_bounds__(1024) void k_front(
        const float* __restrict__ e, const float* __restrict__ rE,
        const float* __restrict__ sup, const float* __restrict__ W1,
        const float* __restrict__ b1, const float* __restrict__ W2,
        const float* __restrict__ b2,
        float* __restrict__ ow, ushort* __restrict__ tmh,
        ushort* __restrict__ tml, float* __restrict__ nm2) {
    const int b = blockIdx.x, tid = threadIdx.x;
    __shared__ unsigned hist[NBUCK];
    __shared__ ull cand[1024];
    __shared__ float rEs[R];
    __shared__ float rpS[H];
    __shared__ int oidxS[K];
    __shared__ float sS[K][D];
    __shared__ float hS[K][H];
    __shared__ unsigned cnt;
    __shared__ int tsh;

    #pragma unroll
    for (int i = 0; i < NBUCK / 1024; ++i) hist[tid + i * 1024] = 0;
    if (tid == 0) cnt = 0;
    if (tid < R) rEs[tid] = rE[b * R + tid];

    // ---- phase A: top-K ----
    ull keys[12];
    int bkt[12];
    const float4* e4 = (const float4*)(e + b * N);
    #pragma unroll
    for (int i = 0; i < 3; ++i) {
        const int fi = tid + i * 1024;
        #pragma unroll
        for (int j = 0; j < 4; ++j) { keys[i * 4 + j] = 0ull; bkt[i * 4 + j] = -1; }
        if (fi < 2500) {                      // 2500 float4 = 10000 elems
            const float4 v4 = e4[fi];
            const float vv[4] = {v4.x, v4.y, v4.z, v4.w};
            #pragma unroll
            for (int j = 0; j < 4; ++j) {
                const int n = fi * 4 + j;
                keys[i * 4 + j] = ((ull)__float_as_uint(vv[j]) << 32) |
                                  (unsigned)(0xFFFFFFFFu - (unsigned)n);
                int bu = (int)(vv[j] * (float)NBUCK);
                bkt[i * 4 + j] = bu > NBUCK - 1 ? NBUCK - 1 : (bu < 0 ? 0 : bu);
            }
        }
    }
    __syncthreads();
    #pragma unroll
    for (int i = 0; i < 12; ++i) if (bkt[i] >= 0) atomicAdd(&hist[bkt[i]], 1u);
    __syncthreads();

    // wave 0: parallel suffix scan from the top, 64 buckets per step
    if (tid < 64) {
        unsigned acc = 0;
        for (int w = 0; w < NBUCK / 64; ++w) {
            const int j = NBUCK - 1 - (w * 64 + tid);
            unsigned p = hist[j];
            #pragma unroll
            for (int off = 1; off < 64; off <<= 1) {
                unsigned o = __shfl_up(p, off, 64);
                if (tid >= off) p += o;
            }
            const ull mask = __ballot(acc + p >= K);
            if (mask) {
                if (tid == 0) {
                    const int l0 = __ffsll((long long)mask) - 1;
                    tsh = NBUCK - 1 - (w * 64 + l0);
                }
                break;
            }
            acc += (unsigned)__shfl((int)p, 63, 64);
        }
    }
    __syncthreads();
    const int t = tsh;

    #pragma unroll
    for (int i = 0; i < 12; ++i)
        if (bkt[i] >= t) {
            unsigned p = atomicAdd(&cnt, 1u);
            if (p < 1024u) cand[p] = keys[i];
        }
    __syncthreads();

    const unsigned C = cnt < 1024u ? cnt : 1024u;
    if (tid < (int)C) {
        const ull mine = cand[tid];
        int rank = 0;
        for (unsigned j = 0; j < C; ++j) rank += (cand[j] > mine);
        if (rank < K) {
            oidxS[rank] = (int)(0xFFFFFFFFu - (unsigned)(mine & 0xFFFFFFFFu));
            ow[b * K + rank] = __uint_as_float((unsigned)(mine >> 32));
        }
    }

    // rp[t] = b1[t] + rE_b . W1[t][0:R]   (independent of selection)
    if (tid < H) {
        const float4* w = (const float4*)(W1 + tid * (R + D));
        float acc = b1[tid];
        #pragma unroll
        for (int i = 0; i < R / 4; ++i) {
            const float4 wv = w[i];
            acc += wv.x * rEs[4 * i] + wv.y * rEs[4 * i + 1] +
                   wv.z * rEs[4 * i + 2] + wv.w * rEs[4 * i + 3];
        }
        rpS[tid] = acc;
    }
    __syncthreads();

    // ---- phase B: MLP on the 32 selected rows ----
    // gather s rows (2 floats per thread, coalesced within rows)
    #pragma unroll
    for (int i = 0; i < 2; ++i) {
        const int f = tid + i * 1024;
        const int r = f >> 6, d = f & 63;
        sS[r][d] = sup[oidxS[r] * D + d];
    }
    __syncthreads();

    {   // phase 1: thread (half, t): h for 16 rows, W1 row loaded once
        const int t = tid & 511, half = tid >> 9;
        const float4* w = (const float4*)(W1 + t * (R + D) + R);
        float4 wv[16];
        #pragma unroll
        for (int i = 0; i < 16; ++i) wv[i] = w[i];
        const float base = rpS[t];
        #pragma unroll
        for (int r = 0; r < 16; ++r) {
            const int row = half * 16 + r;
            float a = base;
            #pragma unroll
            for (int i = 0; i < 16; ++i)
                a += wv[i].x * sS[row][4 * i] + wv[i].y * sS[row][4 * i + 1] +
                     wv[i].z * sS[row][4 * i + 2] + wv[i].w * sS[row][4 * i + 3];
            hS[row][t] = fmaxf(a, 0.f);
        }
    }
    __syncthreads();

    {   // phase 2: wave w owns rows {w, w+16}, lane = d; W2[d] streamed once
        const int d = tid & 63, r0 = tid >> 6, r1 = r0 + 16;
        const float4* w2 = (const float4*)(W2 + d * H);
        float a0 = 0.f, a1 = 0.f;
        #pragma unroll
        for (int c = 0; c < H / 4; ++c) {
            const float4 wv = w2[c];
            a0 += wv.x * hS[r0][4 * c] + wv.y * hS[r0][4 * c + 1] +
                  wv.z * hS[r0][4 * c + 2] + wv.w * hS[r0][4 * c + 3];
            a1 += wv.x * hS[r1][4 * c] + wv.y * hS[r1][4 * c + 1] +
                  wv.z * hS[r1][4 * c + 2] + wv.w * hS[r1][4 * c + 3];
        }
        const float bb = b2[d];
        const float m0 = a0 + bb, m1 = a1 + bb;
        const ushort h0 = f2bf_bits(m0), h1 = f2bf_bits(m1);
        tmh[(b * K + r0) * D + d] = h0;
        tml[(b * K + r0) * D + d] =
            f2bf_bits(m0 - __uint_as_float(((unsigned)h0) << 16));
        tmh[(b * K + r1) * D + d] = h1;
        tml[(b * K + r1) * D + d] =
            f2bf_bits(m1 - __uint_as_float(((unsigned)h1) << 16));
        float q0 = m0 * m0, q1 = m1 * m1;
        #pragma unroll
        for (int off = 32; off > 0; off >>= 1) {
            q0 += __shfl_down(q0, off, 64);
            q1 += __shfl_down(q1, off, 64);
        }
        if (d == 0) {
            nm2[b * K + r0] = -0.5f * q0;
            nm2[b * K + r1] = -0.5f * q1;
        }
    }
}

// ---------------- kernel 2: RBF via 32x32x16 split-bf16 MFMA ----------------
// block = 4 waves x 32 rows = 128 rows, one b. Per wave: C[32n x 32k] via
// 4 k-steps x 3 split products = 12 mfma_f32_32x32x16_bf16 (acc f32x16).
// A: row=lane&31, d = s*16 + (lane>>5)*8 + j (f32 load + in-reg bf16 split).
// B: col(k)=lane&31, same d map. C/D: col=lane&31, row=(r&3)+8*(r>>2)+4*(lane>>5).
// Epilogue: exp, then pairwise tree rowsum -> S_r at lane r32&15==r; one
// coalesced store per half.
__global__ __launch_bounds__(256) void k_rbf(
        const float* __restrict__ sup,
        const ushort* __restrict__ tmh, const ushort* __restrict__ tml,
        const float* __restrict__ nm2, const float* __restrict__ ow,
        float* __restrict__ out, float* __restrict__ part) {
    const int b = blockIdx.y;
    const int tid = threadIdx.x;
    const int lane = tid & 63;
    const int wt = tid >> 6;
    const int g = lane >> 5;                 // d-offset group / row half
    const int r32 = lane & 31;
    const int nb = blockIdx.x * 128 + wt * 32;
    __shared__ float wred[4];

    const int arow = nb + r32;
    const int arowc = arow < N ? arow : N - 1;

    // A: load f32 row chunks, split to bf16 hi/lo in-register
    s16x8 ah[4], al[4];
    float s2o = 0.f;
    const float4* sp = (const float4*)(sup + arowc * D);
    #pragma unroll
    for (int s = 0; s < 4; ++s) {
        const float4 u0 = sp[s * 4 + g * 2];
        const float4 u1 = sp[s * 4 + g * 2 + 1];
        s2o += u0.x * u0.x + u0.y * u0.y + u0.z * u0.z + u0.w * u0.w
             + u1.x * u1.x + u1.y * u1.y + u1.z * u1.z + u1.w * u1.w;
        split8(u0, u1, ah[s], al[s]);
    }
    const float ns2 = -0.5f * (s2o + __shfl_xor(s2o, 32, 64)); // row r32 norm

    // B: bf16 hi/lo fragments of tm row k = r32
    const ushort* ph = tmh + (b * K + r32) * D;
    const ushort* pl = tml + (b * K + r32) * D;
    s16x8 bh[4], bl[4];
    #pragma unroll
    for (int s = 0; s < 4; ++s) {
        bh[s] = *(const s16x8*)(ph + s * 16 + g * 8);
        bl[s] = *(const s16x8*)(pl + s * 16 + g * 8);
    }

    f32x16 acc = {0.f, 0.f, 0.f, 0.f, 0.f, 0.f, 0.f, 0.f,
                  0.f, 0.f, 0.f, 0.f, 0.f, 0.f, 0.f, 0.f};
    #pragma unroll
    for (int s = 0; s < 4; ++s) {            // hi*hi + hi*lo + lo*hi
        acc = __builtin_amdgcn_mfma_f32_32x32x16_bf16(ah[s], bh[s], acc, 0, 0, 0);
        acc = __builtin_amdgcn_mfma_f32_32x32x16_bf16(ah[s], bl[s], acc, 0, 0, 0);
        acc = __builtin_amdgcn_mfma_f32_32x32x16_bf16(al[s], bh[s], acc, 0, 0, 0);
    }

    const float wk = ow[b * K + r32];
    const float qk = nm2[b * K + r32];

    float val[16];
    #pragma unroll
    for (int r = 0; r < 16; ++r) {
        const int rowr = (r & 3) + 8 * (r >> 2) + 4 * g;
        const float nsr = __shfl(ns2, rowr, 64);   // ns2 lives at lane rowr
        val[r] = (nb + rowr) < N ? wk * __expf(nsr + qk + acc[r]) : 0.f;
    }

    // ---- pairwise tree rowsum over the 32 cols ----
    #pragma unroll
    for (int r = 0; r < 16; ++r) val[r] += __shfl_xor(val[r], 16, 64);
    float v8[8];
    #pragma unroll
    for (int i = 0; i < 8; ++i) {
        float t = (r32 & 1) ? val[2 * i] : val[2 * i + 1];
        t = __shfl_xor(t, 1, 64);
        v8[i] = ((r32 & 1) ? val[2 * i + 1] : val[2 * i]) + t;
    }
    float v4[4];
    #pragma unroll
    for (int i = 0; i < 4; ++i) {
        float t = (r32 & 2) ? v8[2 * i] : v8[2 * i + 1];
        t = __shfl_xor(t, 2, 64);
        v4[i] = ((r32 & 2) ? v8[2 * i + 1] : v8[2 * i]) + t;
    }
    float v2[2];
    #pragma unroll
    for (int i = 0; i < 2; ++i) {
        float t = (r32 & 4) ? v4[2 * i] : v4[2 * i + 1];
        t = __shfl_xor(t, 4, 64);
        v2[i] = ((r32 & 4) ? v4[2 * i + 1] : v4[2 * i]) + t;
    }
    float u;
    {
        float t = (r32 & 8) ? v2[0] : v2[1];
        t = __shfl_xor(t, 8, 64);
        u = ((r32 & 8) ? v2[1] : v2[0]) + t;
    }
    // u at lane l = S_{l&15} for rows of half g; one coalesced store
    if (r32 < 16) {
        const int rowr = (r32 & 3) + 8 * (r32 >> 2) + 4 * g;
        const int grow = nb + rowr;
        if (grow < N) out[b * N + grow] = u;
    }
    // wave total: butterfly of u counts each row twice -> x0.5
    float ts = u;
    #pragma unroll
    for (int off = 1; off < 64; off <<= 1) ts += __shfl_xor(ts, off, 64);
    if (lane == 0) wred[wt] = ts * 0.5f;
    __syncthreads();
    if (tid == 0)
        part[b * NRBF + blockIdx.x] = (wred[0] + wred[1]) + (wred[2] + wred[3]);
}

// ---------------- kernel 3: normalize (float4) ----------------
__global__ void k_norm(float* __restrict__ out, const float* __restrict__ part) {
    const int b = blockIdx.y;
    const int tid = threadIdx.x;
    const int f = blockIdx.x * 256 + tid;
    __shared__ float sdiv;
    if (tid < 64) {
        float v = part[b * NRBF + tid];
        if (tid + 64 < NRBF) v += part[b * NRBF + tid + 64];
        #pragma unroll
        for (int off = 32; off > 0; off >>= 1) v += __shfl_down(v, off, 64);
        if (tid == 0) sdiv = 1.f / (v + 1e-10f);
    }
    __syncthreads();
    if (f < N / 4) {
        float4* o4 = (float4*)(out + b * N);
        float4 v = o4[f];
        v.x *= sdiv; v.y *= sdiv; v.z *= sdiv; v.w *= sdiv;
        o4[f] = v;
    }
}

extern "C" void kernel_launch(void* const* d_in, const int* in_sizes, int n_in,
                              void* d_out, int out_size, void* d_ws, size_t ws_size,
                              hipStream_t stream) {
    const float* e   = (const float*)d_in[0];
    const float* rE  = (const float*)d_in[1];
    const float* sup = (const float*)d_in[2];
    const float* W1  = (const float*)d_in[3];
    const float* b1  = (const float*)d_in[4];
    const float* W2  = (const float*)d_in[5];
    const float* b2  = (const float*)d_in[6];
    float* out = (float*)d_out;

    char* ws = (char*)d_ws;
    float*  ow   = (float*)(ws + 0);
    float*  nm2  = (float*)(ws + 2048);
    ushort* tmh  = (ushort*)(ws + 4096);
    ushort* tml  = (ushort*)(ws + 69632);
    float*  part = (float*)(ws + 135168);

    hipLaunchKernelGGL(k_front, dim3(B), dim3(1024), 0, stream,
                       e, rE, sup, W1, b1, W2, b2, ow, tmh, tml, nm2);
    hipLaunchKernelGGL(k_rbf, dim3(NRBF, B), dim3(256), 0, stream,
                       sup, tmh, tml, nm2, ow, out, part);
    hipLaunchKernelGGL(k_norm, dim3(10, B), dim3(256), 0, stream, out, part);
}

// Round 14
// 36.422 us; speedup vs baseline: 2.6364x; 2.6364x over previous
//
#include <hip/hip_runtime.h>
#include <hip/hip_bf16.h>

#define B 16
#define N 10000
#define D 64
#define R 64
#define H 512
#define K 32
#define NRBF 79                      // ceil(10000 / 128) rbf blocks per b
#define NBUCK 4096

typedef unsigned long long ull;
typedef short s16x8 __attribute__((ext_vector_type(8)));
typedef float f32x16 __attribute__((ext_vector_type(16)));

// ---------- ws layout (bytes) ----------
// oidx : B*K int      @ 0        (2048)
// ow   : B*K f32      @ 2048     (2048)
// nm2  : B*K f32      @ 4096     (2048)   -0.5*||mean||^2
// rp   : B*H f32      @ 6144     (32768)  b1 + r_b @ W1[:, :R].T
// tmh  : B*K*D bf16   @ 38912    (65536)  mean hi
// tml  : B*K*D bf16   @ 104448   (65536)  mean lo
// part : B*NRBF f32   @ 169984   (5056)

static __device__ __forceinline__ ushort f2bf_bits(float x) {
    __hip_bfloat16 h = __float2bfloat16(x);
    return *reinterpret_cast<ushort*>(&h);
}
static __device__ __forceinline__ float bf_hi_f(float x) {
    return __bfloat162float(__float2bfloat16(x));
}
// split 8 floats (two float4) into bf16 hi / lo fragments
static __device__ __forceinline__ void split8(const float4 a, const float4 b,
                                              s16x8& hi, s16x8& lo) {
    const float v[8] = {a.x, a.y, a.z, a.w, b.x, b.y, b.z, b.w};
    #pragma unroll
    for (int i = 0; i < 8; ++i) {
        const ushort h = f2bf_bits(v[i]);
        const float hf = __uint_as_float(((unsigned)h) << 16);
        hi[i] = (short)h;
        lo[i] = (short)f2bf_bits(v[i] - hf);
    }
}

// ---------------- kernel 1: exact top-K set + r_part ----------------
// Top-k SET via histogram select (downstream is sum over k -> order
// irrelevant; rank gives value-determined slots; key = val_bits<<32 | ~idx
// preserves jax's smaller-index tie-break). e loaded as float4 (coalesced).
__global__ __launch_bounds__(1024) void k_topk(const float* __restrict__ e,
                                               const float* __restrict__ rE,
                                               const float* __restrict__ W1,
                                               const float* __restrict__ b1,
                                               int* __restrict__ oidx,
                                               float* __restrict__ ow,
                                               float* __restrict__ rp) {
    const int b = blockIdx.x, tid = threadIdx.x;
    __shared__ unsigned hist[NBUCK];
    __shared__ ull cand[1024];
    __shared__ float rEs[R];
    __shared__ unsigned cnt;
    __shared__ int tsh;

    #pragma unroll
    for (int i = 0; i < NBUCK / 1024; ++i) hist[tid + i * 1024] = 0;
    if (tid == 0) cnt = 0;
    if (tid < R) rEs[tid] = rE[b * R + tid];

    // 2500 float4 cover the 10000 elems exactly; 3 vec-loads per thread
    ull keys[12];
    int bkt[12];
    const float4* e4 = (const float4*)(e + b * N);
    #pragma unroll
    for (int i = 0; i < 3; ++i) {
        const int fi = tid + i * 1024;
        #pragma unroll
        for (int j = 0; j < 4; ++j) { keys[i * 4 + j] = 0ull; bkt[i * 4 + j] = -1; }
        if (fi < 2500) {
            const float4 v4 = e4[fi];
            const float vv[4] = {v4.x, v4.y, v4.z, v4.w};
            #pragma unroll
            for (int j = 0; j < 4; ++j) {
                const int n = fi * 4 + j;
                keys[i * 4 + j] = ((ull)__float_as_uint(vv[j]) << 32) |
                                  (unsigned)(0xFFFFFFFFu - (unsigned)n);
                int bu = (int)(vv[j] * (float)NBUCK);
                bkt[i * 4 + j] = bu > NBUCK - 1 ? NBUCK - 1 : (bu < 0 ? 0 : bu);
            }
        }
    }
    __syncthreads();
    #pragma unroll
    for (int i = 0; i < 12; ++i) if (bkt[i] >= 0) atomicAdd(&hist[bkt[i]], 1u);
    __syncthreads();

    // wave 0: parallel suffix scan from the top, 64 buckets per step
    if (tid < 64) {
        unsigned acc = 0;
        for (int w = 0; w < NBUCK / 64; ++w) {
            const int j = NBUCK - 1 - (w * 64 + tid);
            unsigned p = hist[j];
            #pragma unroll
            for (int off = 1; off < 64; off <<= 1) {
                unsigned o = __shfl_up(p, off, 64);
                if (tid >= off) p += o;
            }
            const ull mask = __ballot(acc + p >= K);
            if (mask) {
                if (tid == 0) {
                    const int l0 = __ffsll((long long)mask) - 1;
                    tsh = NBUCK - 1 - (w * 64 + l0);
                }
                break;
            }
            acc += (unsigned)__shfl((int)p, 63, 64);
        }
    }
    __syncthreads();
    const int t = tsh;

    #pragma unroll
    for (int i = 0; i < 12; ++i)
        if (bkt[i] >= t) {
            unsigned p = atomicAdd(&cnt, 1u);
            if (p < 1024u) cand[p] = keys[i];
        }
    __syncthreads();

    const unsigned C = cnt < 1024u ? cnt : 1024u;
    if (tid < (int)C) {
        const ull mine = cand[tid];
        int rank = 0;
        for (unsigned j = 0; j < C; ++j) rank += (cand[j] > mine);
        if (rank < K) {
            oidx[b * K + rank] = (int)(0xFFFFFFFFu - (unsigned)(mine & 0xFFFFFFFFu));
            ow[b * K + rank] = __uint_as_float((unsigned)(mine >> 32));
        }
    }

    // r_part tail (independent of selection; rEs was written pre-barrier)
    if (tid < H) {
        const float4* w = (const float4*)(W1 + tid * (R + D));  // cols 0..R
        float acc = b1[tid];
        #pragma unroll
        for (int i = 0; i < R / 4; ++i) {
            const float4 wv = w[i];
            acc += wv.x * rEs[4 * i] + wv.y * rEs[4 * i + 1] +
                   wv.z * rEs[4 * i + 2] + wv.w * rEs[4 * i + 3];
        }
        rp[b * H + tid] = acc;
    }
}

// ---------------- kernel 2: MLP on selected rows (2 pairs/block) ----------------
// writes mean as bf16 hi/lo (for MFMA) + nm2 = -0.5*||mean||^2 (f32, exact).
__global__ __launch_bounds__(512) void k_means(
        const float* __restrict__ sup, const float* __restrict__ W1,
        const float* __restrict__ W2, const float* __restrict__ b2,
        const int* __restrict__ oidx, const float* __restrict__ rp,
        ushort* __restrict__ tmh, ushort* __restrict__ tml,
        float* __restrict__ nm2) {
    const int b = blockIdx.x >> 4, pr = blockIdx.x & 15;
    const int gk = b * K + pr * 2;
    const int tid = threadIdx.x;
    __shared__ float sA[D], sB[D];
    __shared__ float hA[H], hB[H];
    __shared__ float partA[512], partB[512];

    const int id0 = oidx[gk], id1 = oidx[gk + 1];
    if (tid < D) sA[tid] = sup[id0 * D + tid];
    else if (tid < 2 * D) sB[tid - D] = sup[id1 * D + (tid - D)];
    __syncthreads();

    {   // phase 1: one h-row per thread, weight row read once for both pairs
        const float4* w = (const float4*)(W1 + tid * (R + D) + R);
        float a0 = rp[b * H + tid], a1 = a0;
        #pragma unroll
        for (int i = 0; i < D / 4; ++i) {
            const float4 wv = w[i];
            a0 += wv.x * sA[4 * i] + wv.y * sA[4 * i + 1] +
                  wv.z * sA[4 * i + 2] + wv.w * sA[4 * i + 3];
            a1 += wv.x * sB[4 * i] + wv.y * sB[4 * i + 1] +
                  wv.z * sB[4 * i + 2] + wv.w * sB[4 * i + 3];
        }
        hA[tid] = fmaxf(a0, 0.f);
        hB[tid] = fmaxf(a1, 0.f);
    }
    __syncthreads();

    {   // phase 2: d = tid&63, 8 chunks of 64 over H
        const int d = tid & 63, ch = tid >> 6;
        const float4* w2 = (const float4*)(W2 + d * H + ch * 64);
        float a0 = 0.f, a1 = 0.f;
        #pragma unroll
        for (int i = 0; i < 16; ++i) {
            const float4 wv = w2[i];
            const int hb = ch * 64 + 4 * i;
            a0 += wv.x * hA[hb] + wv.y * hA[hb + 1] + wv.z * hA[hb + 2] + wv.w * hA[hb + 3];
            a1 += wv.x * hB[hb] + wv.y * hB[hb + 1] + wv.z * hB[hb + 2] + wv.w * hB[hb + 3];
        }
        partA[tid] = a0;
        partB[tid] = a1;
    }
    __syncthreads();

    if (tid < 128) {            // wave 0 -> pair 0, wave 1 -> pair 1
        const int d = tid & 63, w = tid >> 6;
        const float* part = w == 0 ? partA : partB;
        float m = b2[d];
        #pragma unroll
        for (int c = 0; c < 8; ++c) m += part[c * 64 + d];
        const float hf = bf_hi_f(m);
        tmh[(gk + w) * D + d] = f2bf_bits(m);
        tml[(gk + w) * D + d] = f2bf_bits(m - hf);
        float sq = m * m;
        #pragma unroll
        for (int off = 32; off > 0; off >>= 1) sq += __shfl_down(sq, off, 64);
        if (d == 0) nm2[gk + w] = -0.5f * sq;
    }
}

// ---------------- kernel 3: RBF via 32x32x16 split-bf16 MFMA ----------------
// block = 4 waves x 32 rows = 128 rows, one b. Per wave: C[32n x 32k] via
// 4 k-steps x 3 split products = 12 mfma_f32_32x32x16_bf16 (acc f32x16).
// A: row=lane&31, d = s*16 + (lane>>5)*8 + j (f32 load + in-reg bf16 split).
// B: col(k)=lane&31, same d map. C/D: col=lane&31, row=(r&3)+8*(r>>2)+4*(lane>>5).
// Epilogue: exp, then pairwise tree rowsum -> S_r at lane r32&15==r; one
// coalesced store per half.
__global__ __launch_bounds__(256) void k_rbf(
        const float* __restrict__ sup,
        const ushort* __restrict__ tmh, const ushort* __restrict__ tml,
        const float* __restrict__ nm2, const float* __restrict__ ow,
        float* __restrict__ out, float* __restrict__ part) {
    const int b = blockIdx.y;
    const int tid = threadIdx.x;
    const int lane = tid & 63;
    const int wt = tid >> 6;
    const int g = lane >> 5;                 // d-offset group / row half
    const int r32 = lane & 31;
    const int nb = blockIdx.x * 128 + wt * 32;
    __shared__ float wred[4];

    const int arow = nb + r32;
    const int arowc = arow < N ? arow : N - 1;

    // A: load f32 row chunks, split to bf16 hi/lo in-register
    s16x8 ah[4], al[4];
    float s2o = 0.f;
    const float4* sp = (const float4*)(sup + arowc * D);
    #pragma unroll
    for (int s = 0; s < 4; ++s) {
        const float4 u0 = sp[s * 4 + g * 2];
        const float4 u1 = sp[s * 4 + g * 2 + 1];
        s2o += u0.x * u0.x + u0.y * u0.y + u0.z * u0.z + u0.w * u0.w
             + u1.x * u1.x + u1.y * u1.y + u1.z * u1.z + u1.w * u1.w;
        split8(u0, u1, ah[s], al[s]);
    }
    const float ns2 = -0.5f * (s2o + __shfl_xor(s2o, 32, 64)); // row r32 norm

    // B: bf16 hi/lo fragments of tm row k = r32
    const ushort* ph = tmh + (b * K + r32) * D;
    const ushort* pl = tml + (b * K + r32) * D;
    s16x8 bh[4], bl[4];
    #pragma unroll
    for (int s = 0; s < 4; ++s) {
        bh[s] = *(const s16x8*)(ph + s * 16 + g * 8);
        bl[s] = *(const s16x8*)(pl + s * 16 + g * 8);
    }

    f32x16 acc = {0.f, 0.f, 0.f, 0.f, 0.f, 0.f, 0.f, 0.f,
                  0.f, 0.f, 0.f, 0.f, 0.f, 0.f, 0.f, 0.f};
    #pragma unroll
    for (int s = 0; s < 4; ++s) {            // hi*hi + hi*lo + lo*hi
        acc = __builtin_amdgcn_mfma_f32_32x32x16_bf16(ah[s], bh[s], acc, 0, 0, 0);
        acc = __builtin_amdgcn_mfma_f32_32x32x16_bf16(ah[s], bl[s], acc, 0, 0, 0);
        acc = __builtin_amdgcn_mfma_f32_32x32x16_bf16(al[s], bh[s], acc, 0, 0, 0);
    }

    const float wk = ow[b * K + r32];
    const float qk = nm2[b * K + r32];

    float val[16];
    #pragma unroll
    for (int r = 0; r < 16; ++r) {
        const int rowr = (r & 3) + 8 * (r >> 2) + 4 * g;
        const float nsr = __shfl(ns2, rowr, 64);   // ns2 lives at lane rowr
        val[r] = (nb + rowr) < N ? wk * __expf(nsr + qk + acc[r]) : 0.f;
    }

    // ---- pairwise tree rowsum over the 32 cols ----
    #pragma unroll
    for (int r = 0; r < 16; ++r) val[r] += __shfl_xor(val[r], 16, 64);
    float v8[8];
    #pragma unroll
    for (int i = 0; i < 8; ++i) {
        float t = (r32 & 1) ? val[2 * i] : val[2 * i + 1];
        t = __shfl_xor(t, 1, 64);
        v8[i] = ((r32 & 1) ? val[2 * i + 1] : val[2 * i]) + t;
    }
    float v4[4];
    #pragma unroll
    for (int i = 0; i < 4; ++i) {
        float t = (r32 & 2) ? v8[2 * i] : v8[2 * i + 1];
        t = __shfl_xor(t, 2, 64);
        v4[i] = ((r32 & 2) ? v8[2 * i + 1] : v8[2 * i]) + t;
    }
    float v2[2];
    #pragma unroll
    for (int i = 0; i < 2; ++i) {
        float t = (r32 & 4) ? v4[2 * i] : v4[2 * i + 1];
        t = __shfl_xor(t, 4, 64);
        v2[i] = ((r32 & 4) ? v4[2 * i + 1] : v4[2 * i]) + t;
    }
    float u;
    {
        float t = (r32 & 8) ? v2[0] : v2[1];
        t = __shfl_xor(t, 8, 64);
        u = ((r32 & 8) ? v2[1] : v2[0]) + t;
    }
    // u at lane l = S_{l&15} for rows of half g; one coalesced store
    if (r32 < 16) {
        const int rowr = (r32 & 3) + 8 * (r32 >> 2) + 4 * g;
        const int grow = nb + rowr;
        if (grow < N) out[b * N + grow] = u;
    }
    // wave total: butterfly of u counts each row twice -> x0.5
    float ts = u;
    #pragma unroll
    for (int off = 1; off < 64; off <<= 1) ts += __shfl_xor(ts, off, 64);
    if (lane == 0) wred[wt] = ts * 0.5f;
    __syncthreads();
    if (tid == 0)
        part[b * NRBF + blockIdx.x] = (wred[0] + wred[1]) + (wred[2] + wred[3]);
}

// ---------------- kernel 4: normalize (float4) ----------------
__global__ void k_norm(float* __restrict__ out, const float* __restrict__ part) {
    const int b = blockIdx.y;
    const int tid = threadIdx.x;
    const int f = blockIdx.x * 256 + tid;
    __shared__ float sdiv;
    if (tid < 64) {
        float v = part[b * NRBF + tid];
        if (tid + 64 < NRBF) v += part[b * NRBF + tid + 64];
        #pragma unroll
        for (int off = 32; off > 0; off >>= 1) v += __shfl_down(v, off, 64);
        if (tid == 0) sdiv = 1.f / (v + 1e-10f);
    }
    __syncthreads();
    if (f < N / 4) {
        float4* o4 = (float4*)(out + b * N);
        float4 v = o4[f];
        v.x *= sdiv; v.y *= sdiv; v.z *= sdiv; v.w *= sdiv;
        o4[f] = v;
    }
}

extern "C" void kernel_launch(void* const* d_in, const int* in_sizes, int n_in,
                              void* d_out, int out_size, void* d_ws, size_t ws_size,
                              hipStream_t stream) {
    const float* e   = (const float*)d_in[0];
    const float* rE  = (const float*)d_in[1];
    const float* sup = (const float*)d_in[2];
    const float* W1  = (const float*)d_in[3];
    const float* b1  = (const float*)d_in[4];
    const float* W2  = (const float*)d_in[5];
    const float* b2  = (const float*)d_in[6];
    float* out = (float*)d_out;

    char* ws = (char*)d_ws;
    int*    oidx = (int*)(ws + 0);
    float*  ow   = (float*)(ws + 2048);
    float*  nm2  = (float*)(ws + 4096);
    float*  rp   = (float*)(ws + 6144);
    ushort* tmh  = (ushort*)(ws + 38912);
    ushort* tml  = (ushort*)(ws + 104448);
    float*  part = (float*)(ws + 169984);

    hipLaunchKernelGGL(k_topk, dim3(B), dim3(1024), 0, stream,
                       e, rE, W1, b1, oidx, ow, rp);
    hipLaunchKernelGGL(k_means, dim3(B * 16), dim3(512), 0, stream,
                       sup, W1, W2, b2, oidx, rp, tmh, tml, nm2);
    hipLaunchKernelGGL(k_rbf, dim3(NRBF, B), dim3(256), 0, stream,
                       sup, tmh, tml, nm2, ow, out, part);
    hipLaunchKernelGGL(k_norm, dim3(10, B), dim3(256), 0, stream, out, part);
}